// Round 2
// baseline (324.443 us; speedup 1.0000x reference)
//
#include <hip/hip_runtime.h>
#include <cmath>

constexpr int ISIZE = 512;
constexpr int REC   = 1024;
constexpr int NACT  = 18;
constexpr int BS    = 64;
constexpr float CLIPVAL = 2.0f;

// batch-group phasing: process GB batches per phase so pass-2's hebb re-read
// hits the 256 MiB Infinity Cache (64 MiB slice/group) instead of HBM.
constexpr int GB      = 16;           // batches per group
constexpr int NGROUPS = BS / GB;      // 4
constexpr int NIC     = 32;           // i-chunks of 32 rows each
constexpr int NXC     = 4;            // x-chunks of 128 k each
constexpr int NC      = NIC + NXC;    // 36 partials per (b,j)

// workspace layout (floats) — identical footprint to the proven R1 layout
constexpr size_t WS_W0T  = 0;                                // 512*1024
constexpr size_t WS_PART = (size_t)ISIZE * REC;              // GB*NC*1024 = 589824
constexpr size_t WS_G    = WS_PART + (size_t)GB * NC * REC;  // 64*1024

// ---------------------------------------------------------------------------
__global__ __launch_bounds__(256) void k_transpose_w0(
    const float* __restrict__ W0, float* __restrict__ W0t) {
  __shared__ float tile[32][33];
  const int bx = blockIdx.x;  // k-tile
  const int by = blockIdx.y;  // j-tile
  const int tx = threadIdx.x;
  const int ty = threadIdx.y;
#pragma unroll
  for (int r = 0; r < 32; r += 8)
    tile[ty + r][tx] = W0[(size_t)(by * 32 + ty + r) * ISIZE + bx * 32 + tx];
  __syncthreads();
#pragma unroll
  for (int r = 0; r < 32; r += 8)
    W0t[(size_t)(bx * 32 + ty + r) * REC + by * 32 + tx] = tile[tx][ty + r];
}

// ---------------------------------------------------------------------------
// Partial sums for one batch group.
// i-chunk blocks (ic<NIC): 32 rows of sum_i rv[b,i]*(w[i,j]+alpha[i,j]*hebb[b,i,j])
// x-chunk blocks (ic>=NIC): 128 k of sum_k x[b,k]*W0t[k,j]
__global__ __launch_bounds__(256) void k_partial(
    const float* __restrict__ rv, const float* __restrict__ hebb,
    const float* __restrict__ w, const float* __restrict__ alpha,
    const float* __restrict__ x, const float* __restrict__ w0t,
    float* __restrict__ part, int gbase) {
  const int ic = blockIdx.x;        // 0..NC-1
  const int bl = blockIdx.y;        // 0..GB-1
  const int b  = gbase + bl;
  const int j0 = threadIdx.x * 4;
  float4 acc = make_float4(0.f, 0.f, 0.f, 0.f);

  if (ic < NIC) {
    const int i0 = ic * 32;
    const float* __restrict__ rvb = rv + (size_t)b * REC;
    const size_t hb = (size_t)b * REC * REC;
#pragma unroll 4
    for (int i = i0; i < i0 + 32; ++i) {
      const float r = rvb[i];
      const float4 wv = *reinterpret_cast<const float4*>(w     + (size_t)i * REC + j0);
      const float4 av = *reinterpret_cast<const float4*>(alpha + (size_t)i * REC + j0);
      const float4 hv = *reinterpret_cast<const float4*>(hebb + hb + (size_t)i * REC + j0);
      acc.x = fmaf(r, fmaf(av.x, hv.x, wv.x), acc.x);
      acc.y = fmaf(r, fmaf(av.y, hv.y, wv.y), acc.y);
      acc.z = fmaf(r, fmaf(av.z, hv.z, wv.z), acc.z);
      acc.w = fmaf(r, fmaf(av.w, hv.w, wv.w), acc.w);
    }
  } else {
    const int k0 = (ic - NIC) * 128;
    const float* __restrict__ xb = x + (size_t)b * ISIZE;
#pragma unroll 4
    for (int k = k0; k < k0 + 128; ++k) {
      const float xv = xb[k];
      const float4 wv = *reinterpret_cast<const float4*>(w0t + (size_t)k * REC + j0);
      acc.x = fmaf(xv, wv.x, acc.x);
      acc.y = fmaf(xv, wv.y, acc.y);
      acc.z = fmaf(xv, wv.z, acc.z);
      acc.w = fmaf(xv, wv.w, acc.w);
    }
  }
  *reinterpret_cast<float4*>(part + ((size_t)bl * NC + ic) * REC + j0) = acc;
}

// ---------------------------------------------------------------------------
// Per-batch (one block per batch in group): reduce partials -> hactiv=tanh(.),
// then logits/softmax, myeta, and g[b,j] = (myeta*mw[j]+mb[j])*hactiv[b,j].
__global__ __launch_bounds__(256) void k_reduce_head(
    const float* __restrict__ part, const float* __restrict__ b0,
    const float* __restrict__ W1, const float* __restrict__ b1,
    const float* __restrict__ h2w, const float* __restrict__ h2b,
    const float* __restrict__ mw, const float* __restrict__ mb,
    float* __restrict__ hact, float* __restrict__ act_dis,
    float* __restrict__ g, int gbase) {
  const int bl = blockIdx.x;
  const int b  = gbase + bl;
  const int t  = threadIdx.x;
  const int j0 = t * 4;

  __shared__ float hsh[REC];
  __shared__ float wsum[4];
  __shared__ float logits[NACT];
  __shared__ float myeta_s;

  // reduce NC partials + b0, tanh
  float4 s = *reinterpret_cast<const float4*>(b0 + j0);
#pragma unroll
  for (int ic = 0; ic < NC; ++ic) {
    const float4 p = *reinterpret_cast<const float4*>(part + ((size_t)bl * NC + ic) * REC + j0);
    s.x += p.x; s.y += p.y; s.z += p.z; s.w += p.w;
  }
  float4 h4;
  h4.x = tanhf(s.x); h4.y = tanhf(s.y); h4.z = tanhf(s.z); h4.w = tanhf(s.w);
  *reinterpret_cast<float4*>(hact + (size_t)b * REC + j0) = h4;
  *reinterpret_cast<float4*>(hsh + j0) = h4;
  __syncthreads();

  const int lane = t & 63;
  const int wid  = t >> 6;

  // logits
  for (int a = 0; a < NACT; ++a) {
    float p = 0.f;
    const float* __restrict__ w1a = W1 + (size_t)a * REC;
    for (int j = t; j < REC; j += 256) p = fmaf(hsh[j], w1a[j], p);
#pragma unroll
    for (int off = 32; off > 0; off >>= 1) p += __shfl_down(p, off);
    if (lane == 0) wsum[wid] = p;
    __syncthreads();
    if (t == 0) logits[a] = wsum[0] + wsum[1] + wsum[2] + wsum[3] + b1[a];
    __syncthreads();
  }

  // myeta
  {
    float p = 0.f;
    for (int j = t; j < REC; j += 256) p = fmaf(hsh[j], h2w[j], p);
#pragma unroll
    for (int off = 32; off > 0; off >>= 1) p += __shfl_down(p, off);
    if (lane == 0) wsum[wid] = p;
    __syncthreads();
    if (t == 0) myeta_s = tanhf(wsum[0] + wsum[1] + wsum[2] + wsum[3] + h2b[0]);
    __syncthreads();
  }

  if (t == 0) {
    float m = logits[0];
    for (int a = 1; a < NACT; ++a) m = fmaxf(m, logits[a]);
    float e[NACT];
    float ssum = 0.f;
    for (int a = 0; a < NACT; ++a) { e[a] = expf(logits[a] - m); ssum += e[a]; }
    const float inv = 1.f / ssum;
    for (int a = 0; a < NACT; ++a) act_dis[(size_t)b * NACT + a] = e[a] * inv;
  }

  const float me = myeta_s;
  for (int j = t; j < REC; j += 256)
    g[(size_t)b * REC + j] = fmaf(me, mw[j], mb[j]) * hsh[j];
}

// ---------------------------------------------------------------------------
// hebb_out[b,i,j] = clip(hebb[b,i,j] + rv[b,i]*g[b,j], -CLIP, CLIP)
__global__ __launch_bounds__(256) void k_hebb(
    const float* __restrict__ hebb, const float* __restrict__ rv,
    const float* __restrict__ g, float* __restrict__ out, int gbase) {
  const int b  = gbase + blockIdx.y;
  const int i0 = blockIdx.x * 8;
  const int j0 = threadIdx.x * 4;
  const float4 gv = *reinterpret_cast<const float4*>(g + (size_t)b * REC + j0);
  const float* __restrict__ rvb = rv + (size_t)b * REC;
  const size_t hb = (size_t)b * REC * REC;
#pragma unroll
  for (int ii = 0; ii < 8; ++ii) {
    const int i = i0 + ii;
    const float r = rvb[i];
    const size_t off = hb + (size_t)i * REC + j0;
    const float4 hv = *reinterpret_cast<const float4*>(hebb + off);
    float4 o;
    o.x = fminf(fmaxf(fmaf(r, gv.x, hv.x), -CLIPVAL), CLIPVAL);
    o.y = fminf(fmaxf(fmaf(r, gv.y, hv.y), -CLIPVAL), CLIPVAL);
    o.z = fminf(fmaxf(fmaf(r, gv.z, hv.z), -CLIPVAL), CLIPVAL);
    o.w = fminf(fmaxf(fmaf(r, gv.w, hv.w), -CLIPVAL), CLIPVAL);
    *reinterpret_cast<float4*>(out + off) = o;
  }
}

// ---------------------------------------------------------------------------
extern "C" void kernel_launch(void* const* d_in, const int* in_sizes, int n_in,
                              void* d_out, int out_size, void* d_ws, size_t ws_size,
                              hipStream_t stream) {
  const float* x     = (const float*)d_in[0];
  const float* rv    = (const float*)d_in[1];
  const float* hebb  = (const float*)d_in[2];
  const float* w     = (const float*)d_in[3];
  const float* alpha = (const float*)d_in[4];
  const float* W0    = (const float*)d_in[5];
  const float* b0    = (const float*)d_in[6];
  const float* W1    = (const float*)d_in[7];
  const float* b1    = (const float*)d_in[8];
  const float* h2w   = (const float*)d_in[9];
  const float* h2b   = (const float*)d_in[10];
  const float* mw    = (const float*)d_in[11];
  const float* mb    = (const float*)d_in[12];

  float* out_act  = (float*)d_out;               // 64*18
  float* out_hact = out_act + (size_t)BS * NACT; // 64*1024
  float* out_hebb = out_hact + (size_t)BS * REC; // 64*1024*1024

  float* ws   = (float*)d_ws;
  float* w0t  = ws + WS_W0T;
  float* part = ws + WS_PART;
  float* g    = ws + WS_G;

  k_transpose_w0<<<dim3(ISIZE / 32, REC / 32), dim3(32, 8), 0, stream>>>(W0, w0t);

  for (int grp = 0; grp < NGROUPS; ++grp) {
    const int gbase = grp * GB;
    k_partial<<<dim3(NC, GB), 256, 0, stream>>>(rv, hebb, w, alpha, x, w0t, part, gbase);
    k_reduce_head<<<GB, 256, 0, stream>>>(part, b0, W1, b1, h2w, h2b, mw, mb,
                                          out_hact, out_act, g, gbase);
    k_hebb<<<dim3(REC / 8, GB), 256, 0, stream>>>(hebb, rv, g, out_hebb, gbase);
  }
}

// Round 3
// 155.493 us; speedup vs baseline: 2.0865x; 2.0865x over previous
//
#include <hip/hip_runtime.h>
#include <cmath>

constexpr int ISIZE = 512;
constexpr int REC   = 1024;
constexpr int NACT  = 18;
constexpr int BS    = 64;
constexpr float CLIPVAL = 2.0f;

constexpr int NSLOT = 17;  // 16 hebb i-chunk partials + 1 x@W0^T partial

// ws budget (floats): part 64*17*1024 = 1,114,112 + g 65,536 = 1,179,648
// == exactly the R1-proven 4.72 MB footprint.

typedef float f4 __attribute__((ext_vector_type(4)));

__device__ __forceinline__ f4 nt_load(const f4* p) {
#if __has_builtin(__builtin_nontemporal_load)
  return __builtin_nontemporal_load(p);
#else
  return *p;
#endif
}
__device__ __forceinline__ void nt_store(f4* p, f4 v) {
#if __has_builtin(__builtin_nontemporal_store)
  __builtin_nontemporal_store(v, p);
#else
  *p = v;
#endif
}

// ---------------------------------------------------------------------------
// Pass 1, single dispatch of 576 blocks:
//   blocks 0..511 : hebb partials. Block = (ic, jh, bg): 64 i-rows x 512 j x
//                   4 batches. Each thread: 4 j (float4) x 2 batches in regs.
//                   bg is the FASTEST block dim so 16 concurrent blocks share
//                   the same w/alpha slice (L2/L3-hot); w/alpha cache traffic
//                   drops 4x vs one-batch-per-block.
//   blocks 512..575: x @ W0^T tiled GEMM (32b x 32j tiles, LDS-transposed W0),
//                   writes partial slot 16.
__global__ __launch_bounds__(256) void k_pass1(
    const float* __restrict__ rv, const float* __restrict__ hebb,
    const float* __restrict__ w, const float* __restrict__ alpha,
    const float* __restrict__ x, const float* __restrict__ W0,
    float* __restrict__ part) {
  const int id = blockIdx.x;
  const int t  = threadIdx.x;

  if (id < 512) {
    const int bg = id & 15;          // fastest: shares w/alpha across batches
    const int jh = (id >> 4) & 1;
    const int ic = id >> 5;
    const int b0 = bg * 4, i0 = ic * 64;
    const int jl = t & 127, bl = t >> 7;   // 128 j-lanes x 2 batch-lanes
    const int j0 = jh * 512 + jl * 4;
    const int ba = b0 + bl * 2;            // this thread's 2 batches: ba, ba+1

    __shared__ float rvs[4][64];
    rvs[t >> 6][t & 63] = rv[(size_t)(b0 + (t >> 6)) * REC + i0 + (t & 63)];
    __syncthreads();

    f4 a0 = {0.f, 0.f, 0.f, 0.f}, a1 = {0.f, 0.f, 0.f, 0.f};
    const float* __restrict__ wp  = w     + (size_t)i0 * REC + j0;
    const float* __restrict__ ap  = alpha + (size_t)i0 * REC + j0;
    const float* __restrict__ hp0 = hebb + ((size_t)ba * REC + i0) * REC + j0;
    const float* __restrict__ hp1 = hp0 + (size_t)REC * REC;
    const float* __restrict__ r0s = &rvs[bl * 2][0];
    const float* __restrict__ r1s = &rvs[bl * 2 + 1][0];

#pragma unroll 4
    for (int ii = 0; ii < 64; ++ii) {
      const f4 wv = *(const f4*)(wp  + (size_t)ii * REC);
      const f4 av = *(const f4*)(ap  + (size_t)ii * REC);
      const f4 h0 = *(const f4*)(hp0 + (size_t)ii * REC);
      const f4 h1 = *(const f4*)(hp1 + (size_t)ii * REC);
      const float r0 = r0s[ii], r1 = r1s[ii];
      a0.x = fmaf(r0, fmaf(av.x, h0.x, wv.x), a0.x);
      a0.y = fmaf(r0, fmaf(av.y, h0.y, wv.y), a0.y);
      a0.z = fmaf(r0, fmaf(av.z, h0.z, wv.z), a0.z);
      a0.w = fmaf(r0, fmaf(av.w, h0.w, wv.w), a0.w);
      a1.x = fmaf(r1, fmaf(av.x, h1.x, wv.x), a1.x);
      a1.y = fmaf(r1, fmaf(av.y, h1.y, wv.y), a1.y);
      a1.z = fmaf(r1, fmaf(av.z, h1.z, wv.z), a1.z);
      a1.w = fmaf(r1, fmaf(av.w, h1.w, wv.w), a1.w);
    }
    *(f4*)(part + ((size_t)ba * NSLOT + ic) * REC + j0)       = a0;
    *(f4*)(part + ((size_t)(ba + 1) * NSLOT + ic) * REC + j0) = a1;

  } else {
    // x @ W0^T -> part slot 16.  idx: 32 j-tiles x 2 batch-halves.
    const int idx = id - 512;
    const int jt = idx & 31, bg2 = idx >> 5;
    const int J0 = jt * 32, B0 = bg2 * 32;
    const int tx = t & 31, ty = t >> 5;    // tx: j/k lane, ty: 0..7
    __shared__ float w0s[32][33];          // [k][j], padded
    __shared__ float xs[32][33];           // [b][k], padded
    float acc[4] = {0.f, 0.f, 0.f, 0.f};
    for (int kk = 0; kk < ISIZE; kk += 32) {
#pragma unroll
      for (int r = 0; r < 32; r += 8) {
        w0s[tx][ty + r] = W0[(size_t)(J0 + ty + r) * ISIZE + kk + tx];
        xs[ty + r][tx]  = x [(size_t)(B0 + ty + r) * ISIZE + kk + tx];
      }
      __syncthreads();
#pragma unroll
      for (int k = 0; k < 32; ++k) {
        const float w0v = w0s[k][tx];
#pragma unroll
        for (int q = 0; q < 4; ++q)
          acc[q] = fmaf(xs[ty * 4 + q][k], w0v, acc[q]);
      }
      __syncthreads();
    }
#pragma unroll
    for (int q = 0; q < 4; ++q)
      part[((size_t)(B0 + ty * 4 + q) * NSLOT + 16) * REC + J0 + tx] = acc[q];
  }
}

// ---------------------------------------------------------------------------
// Per-batch head, 1024 threads: reduce 17 partials + b0 -> tanh -> hactiv;
// logits (wave-per-action), myeta, softmax, g.
__global__ __launch_bounds__(1024) void k_head(
    const float* __restrict__ part, const float* __restrict__ b0,
    const float* __restrict__ W1, const float* __restrict__ b1,
    const float* __restrict__ h2w, const float* __restrict__ h2b,
    const float* __restrict__ mw, const float* __restrict__ mb,
    float* __restrict__ hact, float* __restrict__ act_dis,
    float* __restrict__ g) {
  const int b = blockIdx.x;
  const int t = threadIdx.x;         // == j
  __shared__ float hsh[REC];
  __shared__ float logits_s[32];
  __shared__ float myeta_s;

  float s = b0[t];
  const float* __restrict__ pb = part + (size_t)b * NSLOT * REC + t;
#pragma unroll
  for (int sl = 0; sl < NSLOT; ++sl) s += pb[(size_t)sl * REC];
  const float h = tanhf(s);
  hact[(size_t)b * REC + t] = h;
  hsh[t] = h;
  __syncthreads();

  const int wv = t >> 6, ln = t & 63;
  for (int a = wv; a < NACT; a += 16) {
    const float* __restrict__ w1a = W1 + (size_t)a * REC;
    float p = 0.f;
#pragma unroll
    for (int c = 0; c < 16; ++c) p = fmaf(hsh[c * 64 + ln], w1a[c * 64 + ln], p);
#pragma unroll
    for (int off = 32; off; off >>= 1) p += __shfl_down(p, off);
    if (ln == 0) logits_s[a] = p + b1[a];
  }
  if (wv == 0) {
    float p = 0.f;
#pragma unroll
    for (int c = 0; c < 16; ++c) p = fmaf(hsh[c * 64 + ln], h2w[c * 64 + ln], p);
#pragma unroll
    for (int off = 32; off; off >>= 1) p += __shfl_down(p, off);
    if (ln == 0) myeta_s = tanhf(p + h2b[0]);
  }
  __syncthreads();

  if (t == 0) {
    float m = logits_s[0];
    for (int a = 1; a < NACT; ++a) m = fmaxf(m, logits_s[a]);
    float e[NACT];
    float ssum = 0.f;
    for (int a = 0; a < NACT; ++a) { e[a] = expf(logits_s[a] - m); ssum += e[a]; }
    const float inv = 1.f / ssum;
    for (int a = 0; a < NACT; ++a) act_dis[(size_t)b * NACT + a] = e[a] * inv;
  }

  const float me = myeta_s;
  g[(size_t)b * REC + t] = fmaf(me, mw[t], mb[t]) * hsh[t];
}

// ---------------------------------------------------------------------------
// Pass 2: hebb_out = clip(hebb + rv[b,i]*g[b,j]).
// Block mapping REVERSES pass-1's global hebb read order (i-chunk slow-desc,
// batch fast-desc) so reads start at the L3-LRU-hot tail. Non-temporal
// loads+stores keep pass-2 from evicting the resident pass-1 lines.
__global__ __launch_bounds__(256) void k_hebb(
    const float* __restrict__ hebb, const float* __restrict__ rv,
    const float* __restrict__ g, float* __restrict__ out) {
  const int b  = 63 - (int)blockIdx.x;          // batch: fastest, descending
  const int i0 = (127 - (int)blockIdx.y) * 8;   // i-chunk: slow, descending
  const int j0 = threadIdx.x * 4;
  const f4 gv = *(const f4*)(g + (size_t)b * REC + j0);
  const float* __restrict__ rvb = rv + (size_t)b * REC;
  const size_t base = ((size_t)b * REC + i0) * REC + j0;
#pragma unroll
  for (int ii = 0; ii < 8; ++ii) {
    const float r = rvb[i0 + ii];
    const f4 hv = nt_load((const f4*)(hebb + base + (size_t)ii * REC));
    f4 o;
    o.x = fminf(fmaxf(fmaf(r, gv.x, hv.x), -CLIPVAL), CLIPVAL);
    o.y = fminf(fmaxf(fmaf(r, gv.y, hv.y), -CLIPVAL), CLIPVAL);
    o.z = fminf(fmaxf(fmaf(r, gv.z, hv.z), -CLIPVAL), CLIPVAL);
    o.w = fminf(fmaxf(fmaf(r, gv.w, hv.w), -CLIPVAL), CLIPVAL);
    nt_store((f4*)(out + base + (size_t)ii * REC), o);
  }
}

// ---------------------------------------------------------------------------
extern "C" void kernel_launch(void* const* d_in, const int* in_sizes, int n_in,
                              void* d_out, int out_size, void* d_ws, size_t ws_size,
                              hipStream_t stream) {
  const float* x     = (const float*)d_in[0];
  const float* rv    = (const float*)d_in[1];
  const float* hebb  = (const float*)d_in[2];
  const float* w     = (const float*)d_in[3];
  const float* alpha = (const float*)d_in[4];
  const float* W0    = (const float*)d_in[5];
  const float* b0    = (const float*)d_in[6];
  const float* W1    = (const float*)d_in[7];
  const float* b1    = (const float*)d_in[8];
  const float* h2w   = (const float*)d_in[9];
  const float* h2b   = (const float*)d_in[10];
  const float* mw    = (const float*)d_in[11];
  const float* mb    = (const float*)d_in[12];

  float* out_act  = (float*)d_out;               // 64*18
  float* out_hact = out_act + (size_t)BS * NACT; // 64*1024
  float* out_hebb = out_hact + (size_t)BS * REC; // 64*1024*1024

  float* part = (float*)d_ws;
  float* g    = part + (size_t)BS * NSLOT * REC;

  k_pass1<<<576, 256, 0, stream>>>(rv, hebb, w, alpha, x, W0, part);
  k_head<<<BS, 1024, 0, stream>>>(part, b0, W1, b1, h2w, h2b, mw, mb,
                                  out_hact, out_act, g);
  k_hebb<<<dim3(64, 128), 256, 0, stream>>>(hebb, rv, g, out_hebb);
}